// Round 2
// baseline (3161.957 us; speedup 1.0000x reference)
//
#include <hip/hip_runtime.h>

typedef __attribute__((ext_vector_type(4))) float f32x4;
typedef __attribute__((ext_vector_type(8))) short bf16x8;
typedef __attribute__((ext_vector_type(8))) unsigned short ushort8;

#define NB 16
#define NC 128
#define NT 8
#define NN 1024
#define INV_T (1.0f/0.07f)
#define LDW 40   // LDS row width in ushorts: 32 data + 8 pad (16B) -> <=2-way bank conflict

__device__ __forceinline__ unsigned short f2bf(float x){
  union { float f; unsigned int u; } v; v.f = x;
  unsigned int r = v.u + 0x7fffu + ((v.u >> 16) & 1u);
  return (unsigned short)(r >> 16);
}

// ---------------- K1: normalize over C, write fb[b][t][n][c] bf16 ----------------
__global__ void k_norm(const float* __restrict__ feats, unsigned short* __restrict__ fbuf){
  int n = blockIdx.x * 256 + threadIdx.x;
  int b = blockIdx.y >> 3, t = blockIdx.y & 7;
  const float* src = feats + (((size_t)b * NC) * NT + t) * NN + n;   // feats[b][c][t][n]
  float ss = 0.f;
  #pragma unroll 8
  for(int c = 0; c < NC; c++){ float v = src[(size_t)c * NT * NN]; ss += v * v; }
  float sc = 1.f / (sqrtf(ss) + 1e-12f);
  unsigned short* dst = fbuf + (((size_t)b * NT + t) * NN + n) * NC;
  #pragma unroll 8
  for(int c = 0; c < NC; c++){ float v = src[(size_t)c * NT * NN]; dst[c] = f2bf(v * sc); }
}

// ---------------- LDS staging & fragment helpers ----------------
// 128 rows x 32 ushorts (64B) = 512 chunks of 16B; 256 threads x 2 iters.
__device__ __forceinline__ void stage(const unsigned short* __restrict__ g, int ldg, unsigned short* lds){
  int tid = threadIdx.x;
  #pragma unroll
  for(int j = 0; j < 2; j++){
    int chunk = tid + j * 256;
    int row = chunk >> 2, kc = chunk & 3;
    *(ushort8*)(lds + row * LDW + kc * 8) = *(const ushort8*)(g + (size_t)row * ldg + kc * 8);
  }
}

__device__ __forceinline__ bf16x8 frag(const unsigned short* lds, int r0, int lane){
  return *(const bf16x8*)(lds + (r0 + (lane & 15)) * LDW + (lane >> 4) * 8);
}

// ---------------- K2/K3: G_t[m][k] = exp(<f_{t+1}[m], f_t[k]>/T)  (K=128 GEMM) ----------------
// MODE 0: accumulate sums only: c_t[m]=rowsum(G)=colsum(E), r_t[n]=colsum(G)=rowsum(E)
// MODE 1: store G = E^T bf16
// MODE 2: orientation E0[n][m]; write P0 = E0/(r0[n] r1[m]), M0 = E0/c0[m]
template<int MODE>
__global__ void gemm_small(const unsigned short* __restrict__ fbuf,
                           unsigned short* __restrict__ G,
                           float* __restrict__ rb, float* __restrict__ cb,
                           unsigned short* __restrict__ P0, unsigned short* __restrict__ M0,
                           int tsel)
{
  __shared__ __align__(16) unsigned short lA[128*LDW];
  __shared__ __align__(16) unsigned short lB[128*LDW];
  int b, t;
  if(MODE == 0){ b = blockIdx.z / 7; t = blockIdx.z % 7; }
  else { b = blockIdx.z; t = tsel; }
  int tA = (MODE==2) ? 0 : t+1;
  int tB = (MODE==2) ? 1 : t;
  int brow = blockIdx.x * 128, bcol = blockIdx.y * 128;
  const unsigned short* Ab = fbuf + ((size_t)(b*NT+tA)*NN + brow) * NC;
  const unsigned short* Bb = fbuf + ((size_t)(b*NT+tB)*NN + bcol) * NC;
  int tid = threadIdx.x, lane = tid & 63, w = tid >> 6, wr = w >> 1, wc = w & 1;
  f32x4 acc[4][4];
  #pragma unroll
  for(int m=0;m<4;m++)
    #pragma unroll
    for(int n=0;n<4;n++) acc[m][n] = (f32x4){0.f,0.f,0.f,0.f};

  for(int kk=0; kk<4; kk++){
    __syncthreads();
    stage(Ab + kk*32, NC, lA);
    stage(Bb + kk*32, NC, lB);
    __syncthreads();
    bf16x8 fa[4], fg[4];
    #pragma unroll
    for(int x=0;x<4;x++){ fa[x] = frag(lA, wr*64+x*16, lane); fg[x] = frag(lB, wc*64+x*16, lane); }
    #pragma unroll
    for(int m=0;m<4;m++)
      #pragma unroll
      for(int n=0;n<4;n++)
        acc[m][n] = __builtin_amdgcn_mfma_f32_16x16x32_bf16(fa[m], fg[n], acc[m][n], 0, 0, 0);
  }

  float e[4][4][4];
  #pragma unroll
  for(int m=0;m<4;m++)
    #pragma unroll
    for(int n=0;n<4;n++)
      #pragma unroll
      for(int j=0;j<4;j++) e[m][n][j] = __expf(acc[m][n][j] * INV_T);

  if(MODE == 0){
    float* cbt = cb + ((size_t)b*7 + t) * NN;
    float* rbt = rb + ((size_t)b*7 + t) * NN;
    #pragma unroll
    for(int m=0;m<4;m++)
      #pragma unroll
      for(int j=0;j<4;j++){
        float s = e[m][0][j]+e[m][1][j]+e[m][2][j]+e[m][3][j];
        s += __shfl_xor(s,1); s += __shfl_xor(s,2); s += __shfl_xor(s,4); s += __shfl_xor(s,8);
        if((lane & 15) == 0){
          int row = brow + wr*64 + m*16 + (lane>>4)*4 + j;
          atomicAdd(&cbt[row], s);
        }
      }
    #pragma unroll
    for(int n=0;n<4;n++){
      float s = 0.f;
      #pragma unroll
      for(int m=0;m<4;m++)
        #pragma unroll
        for(int j=0;j<4;j++) s += e[m][n][j];
      s += __shfl_xor(s,16); s += __shfl_xor(s,32);
      if((lane >> 4) == 0){
        int col = bcol + wc*64 + n*16 + lane;
        atomicAdd(&rbt[col], s);
      }
    }
  } else if(MODE == 1){
    unsigned short* Gt = G + ((size_t)b << 20);
    #pragma unroll
    for(int m=0;m<4;m++)
      #pragma unroll
      for(int n=0;n<4;n++)
        #pragma unroll
        for(int j=0;j<4;j++){
          int row = brow + wr*64 + m*16 + (lane>>4)*4 + j;
          int col = bcol + wc*64 + n*16 + (lane&15);
          Gt[(size_t)row * NN + col] = f2bf(e[m][n][j]);
        }
  } else {
    const float* r0 = rb + (size_t)b*7*NN;
    const float* r1 = r0 + NN;
    const float* c0 = cb + (size_t)b*7*NN;
    unsigned short* Pt = P0 + ((size_t)b << 20);
    unsigned short* Mt = M0 + ((size_t)b << 20);
    float r1i[4], c0i[4];
    #pragma unroll
    for(int n=0;n<4;n++){
      int col = bcol + wc*64 + n*16 + (lane&15);
      r1i[n] = 1.f / r1[col];
      c0i[n] = 1.f / c0[col];
    }
    #pragma unroll
    for(int m=0;m<4;m++)
      #pragma unroll
      for(int j=0;j<4;j++){
        int row = brow + wr*64 + m*16 + (lane>>4)*4 + j;
        float r0i = 1.f / r0[row];
        #pragma unroll
        for(int n=0;n<4;n++){
          int col = bcol + wc*64 + n*16 + (lane&15);
          size_t idx = (size_t)row * NN + col;
          Pt[idx] = f2bf(e[m][n][j] * r0i * r1i[n]);
          Mt[idx] = f2bf(e[m][n][j] * c0i[n]);
        }
      }
  }
}

// ---------------- K4: fused dual chain GEMM (K=1024) ----------------
// AccR = P_{i-1} @ E_i ; AccM = M_{i-1} @ E_i   (shared B-operand G_i[m][k] = E_i^T)
// epilogue: Pn = AccR / r_{i+1}[col], Mn = AccM / c_i[col], diag += AccR*Mn rowwise
template<int LAST>
__global__ void k_chain(const unsigned short* __restrict__ P, const unsigned short* __restrict__ M,
                        const unsigned short* __restrict__ G,
                        unsigned short* __restrict__ Pn, unsigned short* __restrict__ Mn,
                        const float* __restrict__ rb, const float* __restrict__ cb,
                        float* __restrict__ diag, int i)
{
  __shared__ __align__(16) unsigned short lP[128*LDW];
  __shared__ __align__(16) unsigned short lM[128*LDW];
  __shared__ __align__(16) unsigned short lG[128*LDW];
  int b = blockIdx.z;
  size_t mb = (size_t)b << 20;
  int brow = blockIdx.x * 128, bcol = blockIdx.y * 128;
  const unsigned short* Pb = P + mb + (size_t)brow * NN;
  const unsigned short* Mb = M + mb + (size_t)brow * NN;
  const unsigned short* Gb = G + mb + (size_t)bcol * NN;
  int tid = threadIdx.x, lane = tid & 63, w = tid >> 6, wr = w >> 1, wc = w & 1;
  f32x4 aP[4][4], aM[4][4];
  #pragma unroll
  for(int m=0;m<4;m++)
    #pragma unroll
    for(int n=0;n<4;n++){ aP[m][n] = (f32x4){0.f,0.f,0.f,0.f}; aM[m][n] = (f32x4){0.f,0.f,0.f,0.f}; }

  for(int kk=0; kk<32; kk++){
    __syncthreads();
    stage(Pb + kk*32, NN, lP);
    stage(Mb + kk*32, NN, lM);
    stage(Gb + kk*32, NN, lG);
    __syncthreads();
    bf16x8 fP[4], fM[4], fG[4];
    #pragma unroll
    for(int x=0;x<4;x++){
      fP[x] = frag(lP, wr*64+x*16, lane);
      fM[x] = frag(lM, wr*64+x*16, lane);
      fG[x] = frag(lG, wc*64+x*16, lane);
    }
    #pragma unroll
    for(int m=0;m<4;m++)
      #pragma unroll
      for(int n=0;n<4;n++){
        aP[m][n] = __builtin_amdgcn_mfma_f32_16x16x32_bf16(fP[m], fG[n], aP[m][n], 0, 0, 0);
        aM[m][n] = __builtin_amdgcn_mfma_f32_16x16x32_bf16(fM[m], fG[n], aM[m][n], 0, 0, 0);
      }
  }

  const float* ccur = cb + ((size_t)b*7 + i) * NN;
  const float* rnxt = rb + ((size_t)b*7 + i + 1) * NN;  // not dereferenced when LAST
  float ci[4], ri[4];
  #pragma unroll
  for(int n=0;n<4;n++){
    int col = bcol + wc*64 + n*16 + (lane&15);
    ci[n] = 1.f / ccur[col];
    ri[n] = LAST ? 0.f : 1.f / rnxt[col];
  }
  float* dg = diag + ((size_t)b*6 + (i-1)) * NN;
  #pragma unroll
  for(int m=0;m<4;m++)
    #pragma unroll
    for(int j=0;j<4;j++){
      int row = brow + wr*64 + m*16 + (lane>>4)*4 + j;
      float s = 0.f;
      #pragma unroll
      for(int n=0;n<4;n++){
        int col = bcol + wc*64 + n*16 + (lane&15);
        float vP = aP[m][n][j];
        float vM = aM[m][n][j] * ci[n];
        s += vP * vM;
        if(!LAST){
          size_t idx = mb + (size_t)row * NN + col;
          Pn[idx] = f2bf(vP * ri[n]);
          Mn[idx] = f2bf(vM);
        }
      }
      s += __shfl_xor(s,1); s += __shfl_xor(s,2); s += __shfl_xor(s,4); s += __shfl_xor(s,8);
      if((lane&15)==0) atomicAdd(&dg[row], s);
    }
}

// ---------------- K5: loss = -mean log(diag + eps) ----------------
__global__ void k_loss(const float* __restrict__ diag, float* __restrict__ out){
  __shared__ float red[16];
  float s = 0.f;
  for(int idx = threadIdx.x; idx < NB*6*NN; idx += 1024) s += __logf(diag[idx] + 1e-20f);
  s += __shfl_xor(s,1); s += __shfl_xor(s,2); s += __shfl_xor(s,4);
  s += __shfl_xor(s,8); s += __shfl_xor(s,16); s += __shfl_xor(s,32);
  if((threadIdx.x & 63) == 0) red[threadIdx.x >> 6] = s;
  __syncthreads();
  if(threadIdx.x == 0){
    float t = 0.f;
    for(int k = 0; k < 16; k++) t += red[k];
    out[0] = -t / (6.0f * NB * NN);
  }
}

__global__ void k_fail(float* out){ out[0] = 1.0e9f; }

extern "C" void kernel_launch(void* const* d_in, const int* in_sizes, int n_in,
                              void* d_out, int out_size, void* d_ws, size_t ws_size,
                              hipStream_t stream) {
  const float* feats = (const float*)d_in[0];
  float* out = (float*)d_out;
  char* ws = (char*)d_ws;
  size_t off = 0;
  auto alloc = [&](size_t bytes) -> char* {
    char* p = ws + off; off += (bytes + 255) & ~(size_t)255; return p;
  };
  unsigned short* fb = (unsigned short*)alloc((size_t)NB*NT*NN*NC*2);   // 33.5 MB
  unsigned short* G  = (unsigned short*)alloc((size_t)NB*NN*NN*2);      // 33.5 MB
  unsigned short* Pa = (unsigned short*)alloc((size_t)NB*NN*NN*2);
  unsigned short* Pbuf = (unsigned short*)alloc((size_t)NB*NN*NN*2);
  unsigned short* Ma = (unsigned short*)alloc((size_t)NB*NN*NN*2);
  unsigned short* Mbuf = (unsigned short*)alloc((size_t)NB*NN*NN*2);
  float* rb = (float*)alloc((size_t)NB*7*NN*4);
  float* cb = (float*)alloc((size_t)NB*7*NN*4);
  float* dg = (float*)alloc((size_t)NB*6*NN*4);
  if(off > ws_size){ k_fail<<<1,1,0,stream>>>(out); return; }

  // zero the accumulated buffers (r, c, diag are contiguous, 256B-aligned sizes)
  hipMemsetAsync(rb, 0, (size_t)NB*7*NN*4 + (size_t)NB*7*NN*4 + (size_t)NB*6*NN*4, stream);

  k_norm<<<dim3(4, NB*NT), 256, 0, stream>>>(feats, fb);
  gemm_small<0><<<dim3(8,8,NB*7), 256, 0, stream>>>(fb, nullptr, rb, cb, nullptr, nullptr, 0);
  gemm_small<2><<<dim3(8,8,NB),   256, 0, stream>>>(fb, nullptr, rb, cb, Pa, Ma, 0);

  unsigned short *Pold = Pa, *Mold = Ma, *Pnew = Pbuf, *Mnew = Mbuf;
  for(int i = 1; i <= 6; i++){
    gemm_small<1><<<dim3(8,8,NB), 256, 0, stream>>>(fb, G, rb, cb, nullptr, nullptr, i);
    if(i < 6)
      k_chain<0><<<dim3(8,8,NB), 256, 0, stream>>>(Pold, Mold, G, Pnew, Mnew, rb, cb, dg, i);
    else
      k_chain<1><<<dim3(8,8,NB), 256, 0, stream>>>(Pold, Mold, G, Pnew, Mnew, rb, cb, dg, i);
    unsigned short* tp = Pold; Pold = Pnew; Pnew = tp;
    unsigned short* tm = Mold; Mold = Mnew; Mnew = tm;
  }
  k_loss<<<1, 1024, 0, stream>>>(dg, out);
}

// Round 3
// 907.756 us; speedup vs baseline: 3.4833x; 3.4833x over previous
//
#include <hip/hip_runtime.h>

typedef __attribute__((ext_vector_type(4))) float f32x4;
typedef __attribute__((ext_vector_type(8))) short bf16x8;
typedef __attribute__((ext_vector_type(8))) unsigned short ushort8;

#define NB 16
#define NC 128
#define NT 8
#define NN 1024
#define INV_T (1.0f/0.07f)
#define LDW 40   // padded LDS row width for gemm_small (reg-staged path)

__device__ __forceinline__ unsigned short f2bf(float x){
  union { float f; unsigned int u; } v; v.f = x;
  unsigned int r = v.u + 0x7fffu + ((v.u >> 16) & 1u);
  return (unsigned short)(r >> 16);
}

__device__ __forceinline__ void gload16(const unsigned short* g, unsigned short* l){
  __builtin_amdgcn_global_load_lds((const __attribute__((address_space(1))) unsigned int*)g,
                                   (__attribute__((address_space(3))) unsigned int*)l,
                                   16, 0, 0);
}

// ---------------- K1: normalize over C, write fb[b][t][n][c] bf16 ----------------
__global__ void k_norm(const float* __restrict__ feats, unsigned short* __restrict__ fbuf){
  int n = blockIdx.x * 256 + threadIdx.x;
  int b = blockIdx.y >> 3, t = blockIdx.y & 7;
  const float* src = feats + (((size_t)b * NC) * NT + t) * NN + n;   // feats[b][c][t][n]
  float ss = 0.f;
  #pragma unroll 8
  for(int c = 0; c < NC; c++){ float v = src[(size_t)c * NT * NN]; ss += v * v; }
  float sc = 1.f / (sqrtf(ss) + 1e-12f);
  unsigned short* dst = fbuf + (((size_t)b * NT + t) * NN + n) * NC;
  #pragma unroll 8
  for(int c = 0; c < NC; c++){ float v = src[(size_t)c * NT * NN]; dst[c] = f2bf(v * sc); }
}

// ---------------- reg-staged LDS helpers for gemm_small (256 thr, 128x32 tiles) ----------------
__device__ __forceinline__ void stage(const unsigned short* __restrict__ g, int ldg, unsigned short* lds){
  int tid = threadIdx.x;
  #pragma unroll
  for(int j = 0; j < 2; j++){
    int chunk = tid + j * 256;
    int row = chunk >> 2, kc = chunk & 3;
    *(ushort8*)(lds + row * LDW + kc * 8) = *(const ushort8*)(g + (size_t)row * ldg + kc * 8);
  }
}

__device__ __forceinline__ bf16x8 frag(const unsigned short* lds, int r0, int lane){
  return *(const bf16x8*)(lds + (r0 + (lane & 15)) * LDW + (lane >> 4) * 8);
}

// ---------------- K2/K3: E_t[m][k] = exp(<f_{t+1}[m], f_t[k]>/T) ----------------
// MODE 0: sums only: c_t[m]=rowsum over k, r_t[k]=colsum over m  (E^T orientation)
// MODE 1: store G = E^T bf16
// MODE 2: orientation E0[n][m]; write P0 = E0/(r0[n] r1[m]), M0 = E0/c0[m]
template<int MODE>
__global__ void gemm_small(const unsigned short* __restrict__ fbuf,
                           unsigned short* __restrict__ G,
                           float* __restrict__ rb, float* __restrict__ cb,
                           unsigned short* __restrict__ P0, unsigned short* __restrict__ M0,
                           int tsel)
{
  __shared__ __align__(16) unsigned short lA[128*LDW];
  __shared__ __align__(16) unsigned short lB[128*LDW];
  int b, t;
  if(MODE == 0){ b = blockIdx.z / 7; t = blockIdx.z % 7; }
  else { b = blockIdx.z; t = tsel; }
  int tA = (MODE==2) ? 0 : t+1;
  int tB = (MODE==2) ? 1 : t;
  int brow = blockIdx.x * 128, bcol = blockIdx.y * 128;
  const unsigned short* Ab = fbuf + ((size_t)(b*NT+tA)*NN + brow) * NC;
  const unsigned short* Bb = fbuf + ((size_t)(b*NT+tB)*NN + bcol) * NC;
  int tid = threadIdx.x, lane = tid & 63, w = tid >> 6, wr = w >> 1, wc = w & 1;
  f32x4 acc[4][4];
  #pragma unroll
  for(int m=0;m<4;m++)
    #pragma unroll
    for(int n=0;n<4;n++) acc[m][n] = (f32x4){0.f,0.f,0.f,0.f};

  for(int kk=0; kk<4; kk++){
    __syncthreads();
    stage(Ab + kk*32, NC, lA);
    stage(Bb + kk*32, NC, lB);
    __syncthreads();
    bf16x8 fa[4], fg[4];
    #pragma unroll
    for(int x=0;x<4;x++){ fa[x] = frag(lA, wr*64+x*16, lane); fg[x] = frag(lB, wc*64+x*16, lane); }
    #pragma unroll
    for(int m=0;m<4;m++)
      #pragma unroll
      for(int n=0;n<4;n++)
        acc[m][n] = __builtin_amdgcn_mfma_f32_16x16x32_bf16(fa[m], fg[n], acc[m][n], 0, 0, 0);
  }

  float e[4][4][4];
  #pragma unroll
  for(int m=0;m<4;m++)
    #pragma unroll
    for(int n=0;n<4;n++)
      #pragma unroll
      for(int j=0;j<4;j++) e[m][n][j] = __expf(acc[m][n][j] * INV_T);

  if(MODE == 0){
    float* cbt = cb + ((size_t)b*7 + t) * NN;
    float* rbt = rb + ((size_t)b*7 + t) * NN;
    #pragma unroll
    for(int m=0;m<4;m++)
      #pragma unroll
      for(int j=0;j<4;j++){
        float s = e[m][0][j]+e[m][1][j]+e[m][2][j]+e[m][3][j];
        s += __shfl_xor(s,1); s += __shfl_xor(s,2); s += __shfl_xor(s,4); s += __shfl_xor(s,8);
        if((lane & 15) == 0){
          int row = brow + wr*64 + m*16 + (lane>>4)*4 + j;
          atomicAdd(&cbt[row], s);
        }
      }
    #pragma unroll
    for(int n=0;n<4;n++){
      float s = 0.f;
      #pragma unroll
      for(int m=0;m<4;m++)
        #pragma unroll
        for(int j=0;j<4;j++) s += e[m][n][j];
      s += __shfl_xor(s,16); s += __shfl_xor(s,32);
      if((lane >> 4) == 0){
        int col = bcol + wc*64 + n*16 + lane;
        atomicAdd(&rbt[col], s);
      }
    }
  } else if(MODE == 1){
    unsigned short* Gt = G + ((size_t)b << 20);
    #pragma unroll
    for(int m=0;m<4;m++)
      #pragma unroll
      for(int n=0;n<4;n++)
        #pragma unroll
        for(int j=0;j<4;j++){
          int row = brow + wr*64 + m*16 + (lane>>4)*4 + j;
          int col = bcol + wc*64 + n*16 + (lane&15);
          Gt[(size_t)row * NN + col] = f2bf(e[m][n][j]);
        }
  } else {
    const float* r0 = rb + (size_t)b*7*NN;
    const float* r1 = r0 + NN;
    const float* c0 = cb + (size_t)b*7*NN;
    unsigned short* Pt = P0 + ((size_t)b << 20);
    unsigned short* Mt = M0 + ((size_t)b << 20);
    float r1i[4], c0i[4];
    #pragma unroll
    for(int n=0;n<4;n++){
      int col = bcol + wc*64 + n*16 + (lane&15);
      r1i[n] = 1.f / r1[col];
      c0i[n] = 1.f / c0[col];
    }
    #pragma unroll
    for(int m=0;m<4;m++)
      #pragma unroll
      for(int j=0;j<4;j++){
        int row = brow + wr*64 + m*16 + (lane>>4)*4 + j;
        float r0i = 1.f / r0[row];
        #pragma unroll
        for(int n=0;n<4;n++){
          int col = bcol + wc*64 + n*16 + (lane&15);
          size_t idx = (size_t)row * NN + col;
          Pt[idx] = f2bf(e[m][n][j] * r0i * r1i[n]);
          Mt[idx] = f2bf(e[m][n][j] * c0i[n]);
        }
      }
  }
}

// ---------------- K4: fused dual chain GEMM, tile 128x256, BK=64, 512 thr ----------------
// AccR = P_{i-1} @ E_i ; AccM = M_{i-1} @ E_i   (shared B-operand G_i[m][k] = E_i^T)
// epilogue: Pn = AccR / r_{i+1}[col], Mn = AccM / c_i[col], diag += AccR*(Mn) rowwise
// blockIdx: x = batch (XCD affinity), y = row-block (128), z = col-block (256)
template<int LAST>
__global__ void __launch_bounds__(512, 2)
k_chain(const unsigned short* __restrict__ P, const unsigned short* __restrict__ M,
        const unsigned short* __restrict__ G,
        unsigned short* __restrict__ Pn, unsigned short* __restrict__ Mn,
        const float* __restrict__ rb, const float* __restrict__ cb,
        float* __restrict__ diag, int i)
{
  __shared__ __align__(16) unsigned short lP[128*64];
  __shared__ __align__(16) unsigned short lM[128*64];
  __shared__ __align__(16) unsigned short lG[256*64];
  int b = blockIdx.x;
  size_t mb = (size_t)b << 20;
  int brow = blockIdx.y * 128, bcol = blockIdx.z * 256;
  const unsigned short* Pb = P + mb + (size_t)brow * NN;
  const unsigned short* Mb = M + mb + (size_t)brow * NN;
  const unsigned short* Gb = G + mb + (size_t)bcol * NN;
  int tid = threadIdx.x, lane = tid & 63, w = tid >> 6, wr = w >> 2, wc = w & 3;
  f32x4 aP[4][4], aM[4][4];
  #pragma unroll
  for(int m=0;m<4;m++)
    #pragma unroll
    for(int n=0;n<4;n++){ aP[m][n] = (f32x4){0.f,0.f,0.f,0.f}; aM[m][n] = (f32x4){0.f,0.f,0.f,0.f}; }

  const unsigned short* lPr = lP + (wr*64 + (lane & 15)) * 64 + (lane >> 4) * 8;
  const unsigned short* lMr = lM + (wr*64 + (lane & 15)) * 64 + (lane >> 4) * 8;
  const unsigned short* lGr = lG + (wc*64 + (lane & 15)) * 64 + (lane >> 4) * 8;

  for(int kk = 0; kk < 16; kk++){
    __syncthreads();
    // stage P,M (128x64 each: 1024 chunks), G (256x64: 2048 chunks); 16B/chunk
    #pragma unroll
    for(int c = 0; c < 2; c++){
      int ch = tid + c*512; int row = ch >> 3, c8 = ch & 7;
      gload16(Pb + (size_t)row*NN + kk*64 + c8*8, lP + ch*8);
    }
    #pragma unroll
    for(int c = 0; c < 2; c++){
      int ch = tid + c*512; int row = ch >> 3, c8 = ch & 7;
      gload16(Mb + (size_t)row*NN + kk*64 + c8*8, lM + ch*8);
    }
    #pragma unroll
    for(int c = 0; c < 4; c++){
      int ch = tid + c*512; int row = ch >> 3, c8 = ch & 7;
      gload16(Gb + (size_t)row*NN + kk*64 + c8*8, lG + ch*8);
    }
    __syncthreads();   // drains vmcnt -> LDS tiles ready
    #pragma unroll
    for(int kh = 0; kh < 2; kh++){
      bf16x8 fP[4], fM[4], fG[4];
      #pragma unroll
      for(int x=0;x<4;x++){
        fP[x] = *(const bf16x8*)(lPr + x*16*64 + kh*32);
        fM[x] = *(const bf16x8*)(lMr + x*16*64 + kh*32);
        fG[x] = *(const bf16x8*)(lGr + x*16*64 + kh*32);
      }
      #pragma unroll
      for(int m=0;m<4;m++)
        #pragma unroll
        for(int n=0;n<4;n++){
          aP[m][n] = __builtin_amdgcn_mfma_f32_16x16x32_bf16(fP[m], fG[n], aP[m][n], 0, 0, 0);
          aM[m][n] = __builtin_amdgcn_mfma_f32_16x16x32_bf16(fM[m], fG[n], aM[m][n], 0, 0, 0);
        }
    }
  }

  const float* ccur = cb + ((size_t)b*7 + i) * NN;
  const float* rnxt = rb + ((size_t)b*7 + i + 1) * NN;  // not dereferenced when LAST
  float ci[4], ri[4];
  #pragma unroll
  for(int n=0;n<4;n++){
    int col = bcol + wc*64 + n*16 + (lane&15);
    ci[n] = 1.f / ccur[col];
    ri[n] = LAST ? 0.f : 1.f / rnxt[col];
  }
  float* dg = diag + ((size_t)b*6 + (i-1)) * NN;
  #pragma unroll
  for(int m=0;m<4;m++)
    #pragma unroll
    for(int j=0;j<4;j++){
      int row = brow + wr*64 + m*16 + (lane>>4)*4 + j;
      float s = 0.f;
      #pragma unroll
      for(int n=0;n<4;n++){
        int col = bcol + wc*64 + n*16 + (lane&15);
        float vP = aP[m][n][j];
        float vM = aM[m][n][j] * ci[n];
        s += vP * vM;
        if(!LAST){
          size_t idx = mb + (size_t)row * NN + col;
          Pn[idx] = f2bf(vP * ri[n]);
          Mn[idx] = f2bf(vM);
        }
      }
      s += __shfl_xor(s,1); s += __shfl_xor(s,2); s += __shfl_xor(s,4); s += __shfl_xor(s,8);
      if((lane&15)==0) atomicAdd(&dg[row], s);
    }
}

// ---------------- K5: loss = -mean log(diag + eps) ----------------
__global__ void k_loss(const float* __restrict__ diag, float* __restrict__ out){
  __shared__ float red[16];
  float s = 0.f;
  for(int idx = threadIdx.x; idx < NB*6*NN; idx += 1024) s += __logf(diag[idx] + 1e-20f);
  s += __shfl_xor(s,1); s += __shfl_xor(s,2); s += __shfl_xor(s,4);
  s += __shfl_xor(s,8); s += __shfl_xor(s,16); s += __shfl_xor(s,32);
  if((threadIdx.x & 63) == 0) red[threadIdx.x >> 6] = s;
  __syncthreads();
  if(threadIdx.x == 0){
    float t = 0.f;
    for(int k = 0; k < 16; k++) t += red[k];
    out[0] = -t / (6.0f * NB * NN);
  }
}

__global__ void k_fail(float* out){ out[0] = 1.0e9f; }

extern "C" void kernel_launch(void* const* d_in, const int* in_sizes, int n_in,
                              void* d_out, int out_size, void* d_ws, size_t ws_size,
                              hipStream_t stream) {
  const float* feats = (const float*)d_in[0];
  float* out = (float*)d_out;
  char* ws = (char*)d_ws;
  size_t off = 0;
  auto alloc = [&](size_t bytes) -> char* {
    char* p = ws + off; off += (bytes + 255) & ~(size_t)255; return p;
  };
  unsigned short* fb = (unsigned short*)alloc((size_t)NB*NT*NN*NC*2);   // 33.5 MB
  unsigned short* G  = (unsigned short*)alloc((size_t)NB*NN*NN*2);      // 33.5 MB
  unsigned short* Pa = (unsigned short*)alloc((size_t)NB*NN*NN*2);
  unsigned short* Pbuf = (unsigned short*)alloc((size_t)NB*NN*NN*2);
  unsigned short* Ma = (unsigned short*)alloc((size_t)NB*NN*NN*2);
  unsigned short* Mbuf = (unsigned short*)alloc((size_t)NB*NN*NN*2);
  float* rb = (float*)alloc((size_t)NB*7*NN*4);
  float* cb = (float*)alloc((size_t)NB*7*NN*4);
  float* dg = (float*)alloc((size_t)NB*6*NN*4);
  if(off > ws_size){ k_fail<<<1,1,0,stream>>>(out); return; }

  // zero the accumulated buffers (r, c, diag are contiguous, 256B-aligned sizes)
  hipMemsetAsync(rb, 0, (size_t)NB*7*NN*4 + (size_t)NB*7*NN*4 + (size_t)NB*6*NN*4, stream);

  k_norm<<<dim3(4, NB*NT), 256, 0, stream>>>(feats, fb);
  gemm_small<0><<<dim3(8,8,NB*7), 256, 0, stream>>>(fb, nullptr, rb, cb, nullptr, nullptr, 0);
  gemm_small<2><<<dim3(8,8,NB),   256, 0, stream>>>(fb, nullptr, rb, cb, Pa, Ma, 0);

  unsigned short *Pold = Pa, *Mold = Ma, *Pnew = Pbuf, *Mnew = Mbuf;
  for(int i = 1; i <= 6; i++){
    gemm_small<1><<<dim3(8,8,NB), 256, 0, stream>>>(fb, G, rb, cb, nullptr, nullptr, i);
    if(i < 6)
      k_chain<0><<<dim3(NB, 8, 4), 512, 0, stream>>>(Pold, Mold, G, Pnew, Mnew, rb, cb, dg, i);
    else
      k_chain<1><<<dim3(NB, 8, 4), 512, 0, stream>>>(Pold, Mold, G, Pnew, Mnew, rb, cb, dg, i);
    unsigned short* tp = Pold; Pold = Pnew; Pnew = tp;
    unsigned short* tm = Mold; Mold = Mnew; Mnew = tm;
  }
  k_loss<<<1, 1024, 0, stream>>>(dg, out);
}

// Round 4
// 689.733 us; speedup vs baseline: 4.5843x; 1.3161x over previous
//
#include <hip/hip_runtime.h>

typedef __attribute__((ext_vector_type(4))) float f32x4;
typedef __attribute__((ext_vector_type(8))) short bf16x8;
typedef __attribute__((ext_vector_type(8))) unsigned short ushort8;

#define NB 16
#define NC 128
#define NT 8
#define NN 1024
#define INV_T (1.0f/0.07f)
#define LDW 40   // padded LDS row width for gemm_small (reg-staged path)

__device__ __forceinline__ unsigned short f2bf(float x){
  union { float f; unsigned int u; } v; v.f = x;
  unsigned int r = v.u + 0x7fffu + ((v.u >> 16) & 1u);
  return (unsigned short)(r >> 16);
}

__device__ __forceinline__ void gload16(const unsigned short* g, unsigned short* l){
  __builtin_amdgcn_global_load_lds((const __attribute__((address_space(1))) unsigned int*)g,
                                   (__attribute__((address_space(3))) unsigned int*)l,
                                   16, 0, 0);
}

// ---------------- K1: normalize over C, write fb[b][t][n][c] bf16 ----------------
__global__ void k_norm(const float* __restrict__ feats, unsigned short* __restrict__ fbuf){
  int n = blockIdx.x * 256 + threadIdx.x;
  int b = blockIdx.y >> 3, t = blockIdx.y & 7;
  const float* src = feats + (((size_t)b * NC) * NT + t) * NN + n;   // feats[b][c][t][n]
  float ss = 0.f;
  #pragma unroll 8
  for(int c = 0; c < NC; c++){ float v = src[(size_t)c * NT * NN]; ss += v * v; }
  float sc = 1.f / (sqrtf(ss) + 1e-12f);
  unsigned short* dst = fbuf + (((size_t)b * NT + t) * NN + n) * NC;
  #pragma unroll 8
  for(int c = 0; c < NC; c++){ float v = src[(size_t)c * NT * NN]; dst[c] = f2bf(v * sc); }
}

// ---------------- reg-staged LDS helpers for gemm_small (256 thr, 128x32 tiles) ----------------
__device__ __forceinline__ void stage_s(const unsigned short* __restrict__ g, int ldg, unsigned short* lds){
  int tid = threadIdx.x;
  #pragma unroll
  for(int j = 0; j < 2; j++){
    int chunk = tid + j * 256;
    int row = chunk >> 2, kc = chunk & 3;
    *(ushort8*)(lds + row * LDW + kc * 8) = *(const ushort8*)(g + (size_t)row * ldg + kc * 8);
  }
}

__device__ __forceinline__ bf16x8 frag_s(const unsigned short* lds, int r0, int lane){
  return *(const bf16x8*)(lds + (r0 + (lane & 15)) * LDW + (lane >> 4) * 8);
}

// ---------------- K2/K3: E_t[m][k] = exp(<f_{t+1}[m], f_t[k]>/T) ----------------
// MODE 0: sums: c_t[m]=rowsum over k, r_t[k]=colsum over m; ALSO store G_t for t>=1 if Gall
// MODE 1: store G = E^T bf16 (fallback path)
// MODE 2: orientation E0[n][m]; write P0 = E0/(r0[n] r1[m]), M0 = E0/c0[m]
template<int MODE>
__global__ void gemm_small(const unsigned short* __restrict__ fbuf,
                           unsigned short* __restrict__ G,
                           float* __restrict__ rb, float* __restrict__ cb,
                           unsigned short* __restrict__ P0, unsigned short* __restrict__ M0,
                           int tsel)
{
  __shared__ __align__(16) unsigned short lA[128*LDW];
  __shared__ __align__(16) unsigned short lB[128*LDW];
  int b, t;
  if(MODE == 0){ b = blockIdx.z / 7; t = blockIdx.z % 7; }
  else { b = blockIdx.z; t = tsel; }
  int tA = (MODE==2) ? 0 : t+1;
  int tB = (MODE==2) ? 1 : t;
  int brow = blockIdx.x * 128, bcol = blockIdx.y * 128;
  const unsigned short* Ab = fbuf + ((size_t)(b*NT+tA)*NN + brow) * NC;
  const unsigned short* Bb = fbuf + ((size_t)(b*NT+tB)*NN + bcol) * NC;
  int tid = threadIdx.x, lane = tid & 63, w = tid >> 6, wr = w >> 1, wc = w & 1;
  f32x4 acc[4][4];
  #pragma unroll
  for(int m=0;m<4;m++)
    #pragma unroll
    for(int n=0;n<4;n++) acc[m][n] = (f32x4){0.f,0.f,0.f,0.f};

  for(int kk=0; kk<4; kk++){
    __syncthreads();
    stage_s(Ab + kk*32, NC, lA);
    stage_s(Bb + kk*32, NC, lB);
    __syncthreads();
    bf16x8 fa[4], fg[4];
    #pragma unroll
    for(int x=0;x<4;x++){ fa[x] = frag_s(lA, wr*64+x*16, lane); fg[x] = frag_s(lB, wc*64+x*16, lane); }
    #pragma unroll
    for(int m=0;m<4;m++)
      #pragma unroll
      for(int n=0;n<4;n++)
        acc[m][n] = __builtin_amdgcn_mfma_f32_16x16x32_bf16(fa[m], fg[n], acc[m][n], 0, 0, 0);
  }

  float e[4][4][4];
  #pragma unroll
  for(int m=0;m<4;m++)
    #pragma unroll
    for(int n=0;n<4;n++)
      #pragma unroll
      for(int j=0;j<4;j++) e[m][n][j] = __expf(acc[m][n][j] * INV_T);

  if(MODE == 0){
    float* cbt = cb + ((size_t)b*7 + t) * NN;
    float* rbt = rb + ((size_t)b*7 + t) * NN;
    #pragma unroll
    for(int m=0;m<4;m++)
      #pragma unroll
      for(int j=0;j<4;j++){
        float s = e[m][0][j]+e[m][1][j]+e[m][2][j]+e[m][3][j];
        s += __shfl_xor(s,1); s += __shfl_xor(s,2); s += __shfl_xor(s,4); s += __shfl_xor(s,8);
        if((lane & 15) == 0){
          int row = brow + wr*64 + m*16 + (lane>>4)*4 + j;
          atomicAdd(&cbt[row], s);
        }
      }
    #pragma unroll
    for(int n=0;n<4;n++){
      float s = 0.f;
      #pragma unroll
      for(int m=0;m<4;m++)
        #pragma unroll
        for(int j=0;j<4;j++) s += e[m][n][j];
      s += __shfl_xor(s,16); s += __shfl_xor(s,32);
      if((lane >> 4) == 0){
        int col = bcol + wc*64 + n*16 + lane;
        atomicAdd(&rbt[col], s);
      }
    }
    if(G && t >= 1){   // fused G_t store (big-ws path)
      unsigned short* Gt = G + ((size_t)(t-1)*NB + b) * ((size_t)NN*NN);
      #pragma unroll
      for(int m=0;m<4;m++)
        #pragma unroll
        for(int n=0;n<4;n++)
          #pragma unroll
          for(int j=0;j<4;j++){
            int row = brow + wr*64 + m*16 + (lane>>4)*4 + j;
            int col = bcol + wc*64 + n*16 + (lane&15);
            Gt[(size_t)row * NN + col] = f2bf(e[m][n][j]);
          }
    }
  } else if(MODE == 1){
    unsigned short* Gt = G + ((size_t)b << 20);
    #pragma unroll
    for(int m=0;m<4;m++)
      #pragma unroll
      for(int n=0;n<4;n++)
        #pragma unroll
        for(int j=0;j<4;j++){
          int row = brow + wr*64 + m*16 + (lane>>4)*4 + j;
          int col = bcol + wc*64 + n*16 + (lane&15);
          Gt[(size_t)row * NN + col] = f2bf(e[m][n][j]);
        }
  } else {
    const float* r0 = rb + (size_t)b*7*NN;
    const float* r1 = r0 + NN;
    const float* c0 = cb + (size_t)b*7*NN;
    unsigned short* Pt = P0 + ((size_t)b << 20);
    unsigned short* Mt = M0 + ((size_t)b << 20);
    float r1i[4], c0i[4];
    #pragma unroll
    for(int n=0;n<4;n++){
      int col = bcol + wc*64 + n*16 + (lane&15);
      r1i[n] = 1.f / r1[col];
      c0i[n] = 1.f / c0[col];
    }
    #pragma unroll
    for(int m=0;m<4;m++)
      #pragma unroll
      for(int j=0;j<4;j++){
        int row = brow + wr*64 + m*16 + (lane>>4)*4 + j;
        float r0i = 1.f / r0[row];
        #pragma unroll
        for(int n=0;n<4;n++){
          int col = bcol + wc*64 + n*16 + (lane&15);
          size_t idx = (size_t)row * NN + col;
          Pt[idx] = f2bf(e[m][n][j] * r0i * r1i[n]);
          Mt[idx] = f2bf(e[m][n][j] * c0i[n]);
        }
      }
  }
}

// ---------------- K4: fused dual chain GEMM, tile 128x256, BK=64, 512 thr ----------------
// Double-buffered LDS (128KB), T2 both-sides swizzle, XCD-affinity grid:
//   blockIdx.x = b*4 + colblock  (siblings sharing G panel land on same XCD via linear%8)
//   blockIdx.y = rowblock
template<int LAST>
__global__ void __launch_bounds__(512, 2)
k_chain(const unsigned short* __restrict__ P, const unsigned short* __restrict__ M,
        const unsigned short* __restrict__ G,
        unsigned short* __restrict__ Pn, unsigned short* __restrict__ Mn,
        const float* __restrict__ rb, const float* __restrict__ cb,
        float* __restrict__ diag, int i)
{
  __shared__ __align__(16) unsigned short lP0[128*64], lM0[128*64], lG0[256*64];
  __shared__ __align__(16) unsigned short lP1[128*64], lM1[128*64], lG1[256*64];
  int b  = blockIdx.x >> 2;
  int cbk = blockIdx.x & 3;
  size_t mb = (size_t)b << 20;
  int brow = blockIdx.y * 128, bcol = cbk * 256;
  const unsigned short* Pb = P + mb + (size_t)brow * NN;
  const unsigned short* Mb = M + mb + (size_t)brow * NN;
  const unsigned short* Gb = G + mb + (size_t)bcol * NN;
  int tid = threadIdx.x, lane = tid & 63, w = tid >> 6, wr = w >> 2, wc = w & 3;
  int l15 = lane & 15;

  // staging geometry: chunk = 16B; srow = tid>>3 (0..63); swizzled source chunk g
  int srow = tid >> 3;
  int g8 = (((tid & 7) ^ (srow & 7)) << 3);   // ushort offset of swizzled 16B chunk
  // read-side swizzle: chunk index co0 ^ (kh*4), co0 = (lane>>4) ^ (lane&7)
  int co0 = ((lane >> 4) ^ (lane & 7)) << 3;  // ushort offset

  f32x4 aP[4][4], aM[4][4];
  #pragma unroll
  for(int m=0;m<4;m++)
    #pragma unroll
    for(int n=0;n<4;n++){ aP[m][n] = (f32x4){0.f,0.f,0.f,0.f}; aM[m][n] = (f32x4){0.f,0.f,0.f,0.f}; }

  auto stage = [&](int kk, unsigned short* lp, unsigned short* lm, unsigned short* lg){
    const unsigned short* ps = Pb + kk*64 + g8;
    const unsigned short* ms = Mb + kk*64 + g8;
    const unsigned short* gs = Gb + kk*64 + g8;
    gload16(ps + (size_t)srow*NN,      lp + tid*8);
    gload16(ps + (size_t)(srow+64)*NN, lp + (tid+512)*8);
    gload16(ms + (size_t)srow*NN,      lm + tid*8);
    gload16(ms + (size_t)(srow+64)*NN, lm + (tid+512)*8);
    #pragma unroll
    for(int c = 0; c < 4; c++)
      gload16(gs + (size_t)(srow+c*64)*NN, lg + (tid+c*512)*8);
  };

  auto compute = [&](const unsigned short* lp, const unsigned short* lm, const unsigned short* lg){
    #pragma unroll
    for(int kh = 0; kh < 2; kh++){
      int cOff = co0 ^ (kh << 5);   // (co0_chunk ^ (kh*4)) * 8 ushorts
      bf16x8 fP[4], fM[4], fG[4];
      #pragma unroll
      for(int x=0;x<4;x++){
        fP[x] = *(const bf16x8*)(lp + (wr*64 + x*16 + l15)*64 + cOff);
        fM[x] = *(const bf16x8*)(lm + (wr*64 + x*16 + l15)*64 + cOff);
        fG[x] = *(const bf16x8*)(lg + (wc*64 + x*16 + l15)*64 + cOff);
      }
      #pragma unroll
      for(int m=0;m<4;m++)
        #pragma unroll
        for(int n=0;n<4;n++){
          aP[m][n] = __builtin_amdgcn_mfma_f32_16x16x32_bf16(fP[m], fG[n], aP[m][n], 0, 0, 0);
          aM[m][n] = __builtin_amdgcn_mfma_f32_16x16x32_bf16(fM[m], fG[n], aM[m][n], 0, 0, 0);
        }
    }
  };

  stage(0, lP0, lM0, lG0);
  __syncthreads();
  #pragma unroll 1
  for(int kk = 0; kk < 16; kk += 2){
    if(kk + 1 < 16) stage(kk+1, lP1, lM1, lG1);
    compute(lP0, lM0, lG0);
    __syncthreads();
    if(kk + 2 < 16) stage(kk+2, lP0, lM0, lG0);
    compute(lP1, lM1, lG1);
    __syncthreads();
  }

  const float* ccur = cb + ((size_t)b*7 + i) * NN;
  const float* rnxt = rb + ((size_t)b*7 + i + 1) * NN;  // not dereferenced when LAST
  float ci[4], ri[4];
  #pragma unroll
  for(int n=0;n<4;n++){
    int col = bcol + wc*64 + n*16 + l15;
    ci[n] = 1.f / ccur[col];
    ri[n] = LAST ? 0.f : 1.f / rnxt[col];
  }
  float* dg = diag + ((size_t)b*6 + (i-1)) * NN;
  #pragma unroll
  for(int m=0;m<4;m++)
    #pragma unroll
    for(int j=0;j<4;j++){
      int row = brow + wr*64 + m*16 + (lane>>4)*4 + j;
      float s = 0.f;
      #pragma unroll
      for(int n=0;n<4;n++){
        int col = bcol + wc*64 + n*16 + l15;
        float vP = aP[m][n][j];
        float vM = aM[m][n][j] * ci[n];
        s += vP * vM;
        if(!LAST){
          size_t idx = mb + (size_t)row * NN + col;
          Pn[idx] = f2bf(vP * ri[n]);
          Mn[idx] = f2bf(vM);
        }
      }
      s += __shfl_xor(s,1); s += __shfl_xor(s,2); s += __shfl_xor(s,4); s += __shfl_xor(s,8);
      if((lane&15)==0) atomicAdd(&dg[row], s);
    }
}

// ---------------- K5: loss = -mean log(diag + eps) ----------------
__global__ void k_loss(const float* __restrict__ diag, float* __restrict__ out){
  __shared__ float red[16];
  float s = 0.f;
  for(int idx = threadIdx.x; idx < NB*6*NN; idx += 1024) s += __logf(diag[idx] + 1e-20f);
  s += __shfl_xor(s,1); s += __shfl_xor(s,2); s += __shfl_xor(s,4);
  s += __shfl_xor(s,8); s += __shfl_xor(s,16); s += __shfl_xor(s,32);
  if((threadIdx.x & 63) == 0) red[threadIdx.x >> 6] = s;
  __syncthreads();
  if(threadIdx.x == 0){
    float t = 0.f;
    for(int k = 0; k < 16; k++) t += red[k];
    out[0] = -t / (6.0f * NB * NN);
  }
}

__global__ void k_fail(float* out){ out[0] = 1.0e9f; }

extern "C" void kernel_launch(void* const* d_in, const int* in_sizes, int n_in,
                              void* d_out, int out_size, void* d_ws, size_t ws_size,
                              hipStream_t stream) {
  const float* feats = (const float*)d_in[0];
  float* out = (float*)d_out;
  char* ws = (char*)d_ws;
  size_t off = 0;
  auto alloc = [&](size_t bytes) -> char* {
    char* p = ws + off; off += (bytes + 255) & ~(size_t)255; return p;
  };
  const size_t plane = (size_t)NB * NN * NN * 2;                        // 33.5 MB
  unsigned short* fb = (unsigned short*)alloc((size_t)NB*NT*NN*NC*2);   // 33.5 MB
  unsigned short* Pa   = (unsigned short*)alloc(plane);
  unsigned short* Pbuf = (unsigned short*)alloc(plane);
  unsigned short* Ma   = (unsigned short*)alloc(plane);
  unsigned short* Mbuf = (unsigned short*)alloc(plane);
  float* rb = (float*)alloc((size_t)NB*7*NN*4);
  float* cb = (float*)alloc((size_t)NB*7*NN*4);
  float* dg = (float*)alloc((size_t)NB*6*NN*4);
  if(off + plane > ws_size){ k_fail<<<1,1,0,stream>>>(out); return; }
  bool big = (off + 6*plane) <= ws_size;
  unsigned short* G = (unsigned short*)alloc(big ? 6*plane : plane);

  // zero the accumulated buffers (r, c, diag are contiguous, 256B-aligned sizes)
  hipMemsetAsync(rb, 0, (size_t)NB*7*NN*4 + (size_t)NB*7*NN*4 + (size_t)NB*6*NN*4, stream);

  k_norm<<<dim3(4, NB*NT), 256, 0, stream>>>(feats, fb);
  gemm_small<0><<<dim3(8,8,NB*7), 256, 0, stream>>>(fb, big ? G : nullptr, rb, cb, nullptr, nullptr, 0);
  gemm_small<2><<<dim3(8,8,NB),   256, 0, stream>>>(fb, nullptr, rb, cb, Pa, Ma, 0);

  unsigned short *Pold = Pa, *Mold = Ma, *Pnew = Pbuf, *Mnew = Mbuf;
  for(int i = 1; i <= 6; i++){
    unsigned short* Gi;
    if(big){
      Gi = G + (size_t)(i-1) * NB * NN * NN;
    } else {
      gemm_small<1><<<dim3(8,8,NB), 256, 0, stream>>>(fb, G, rb, cb, nullptr, nullptr, i);
      Gi = G;
    }
    if(i < 6)
      k_chain<0><<<dim3(64, 8), 512, 0, stream>>>(Pold, Mold, Gi, Pnew, Mnew, rb, cb, dg, i);
    else
      k_chain<1><<<dim3(64, 8), 512, 0, stream>>>(Pold, Mold, Gi, Pnew, Mnew, rb, cb, dg, i);
    unsigned short* tp = Pold; Pold = Pnew; Pnew = tp;
    unsigned short* tm = Mold; Mold = Mnew; Mnew = tm;
  }
  k_loss<<<1, 1024, 0, stream>>>(dg, out);
}

// Round 5
// 671.987 us; speedup vs baseline: 4.7054x; 1.0264x over previous
//
#include <hip/hip_runtime.h>

typedef __attribute__((ext_vector_type(4))) float f32x4;
typedef __attribute__((ext_vector_type(8))) short bf16x8;
typedef __attribute__((ext_vector_type(8))) unsigned short ushort8;

#define NB 16
#define NC 128
#define NT 8
#define NN 1024
#define INV_T (1.0f/0.07f)
#define LDW 40   // padded LDS row width for gemm_small (reg-staged path)

__device__ __forceinline__ unsigned short f2bf(float x){
  union { float f; unsigned int u; } v; v.f = x;
  unsigned int r = v.u + 0x7fffu + ((v.u >> 16) & 1u);
  return (unsigned short)(r >> 16);
}

__device__ __forceinline__ void gload16(const unsigned short* g, unsigned short* l){
  __builtin_amdgcn_global_load_lds((const __attribute__((address_space(1))) unsigned int*)g,
                                   (__attribute__((address_space(3))) unsigned int*)l,
                                   16, 0, 0);
}

// ---------------- K1: normalize over C, write fb[b][t][n][c] bf16 ----------------
__global__ void k_norm(const float* __restrict__ feats, unsigned short* __restrict__ fbuf){
  int n = blockIdx.x * 256 + threadIdx.x;
  int b = blockIdx.y >> 3, t = blockIdx.y & 7;
  const float* src = feats + (((size_t)b * NC) * NT + t) * NN + n;   // feats[b][c][t][n]
  float ss = 0.f;
  #pragma unroll 8
  for(int c = 0; c < NC; c++){ float v = src[(size_t)c * NT * NN]; ss += v * v; }
  float sc = 1.f / (sqrtf(ss) + 1e-12f);
  unsigned short* dst = fbuf + (((size_t)b * NT + t) * NN + n) * NC;
  #pragma unroll 8
  for(int c = 0; c < NC; c++){ float v = src[(size_t)c * NT * NN]; dst[c] = f2bf(v * sc); }
}

// ---------------- reg-staged LDS helpers for gemm_small (256 thr, 128x32 tiles) ----------------
__device__ __forceinline__ void stage_s(const unsigned short* __restrict__ g, int ldg, unsigned short* lds){
  int tid = threadIdx.x;
  #pragma unroll
  for(int j = 0; j < 2; j++){
    int chunk = tid + j * 256;
    int row = chunk >> 2, kc = chunk & 3;
    *(ushort8*)(lds + row * LDW + kc * 8) = *(const ushort8*)(g + (size_t)row * ldg + kc * 8);
  }
}

__device__ __forceinline__ bf16x8 frag_s(const unsigned short* lds, int r0, int lane){
  return *(const bf16x8*)(lds + (r0 + (lane & 15)) * LDW + (lane >> 4) * 8);
}

// ---------------- K2/K3: E_t[m][k] = exp(<f_{t+1}[m], f_t[k]>/T) ----------------
// MODE 0: sums: c_t[m]=rowsum over k, r_t[k]=colsum over m; ALSO store G_t for t>=1 if Gall
//         1D grid 7168, XCD-grouped by (b,t)
// MODE 1: store G = E^T bf16 (fallback path, 3D grid)
// MODE 2: orientation E0[n][m]; write P0 = E0/(r0[n] r1[m]), M0 = E0/c0[m]
//         1D grid 1024, XCD-grouped by b
template<int MODE>
__global__ void gemm_small(const unsigned short* __restrict__ fbuf,
                           unsigned short* __restrict__ G,
                           float* __restrict__ rb, float* __restrict__ cb,
                           unsigned short* __restrict__ P0, unsigned short* __restrict__ M0,
                           int tsel)
{
  __shared__ __align__(16) unsigned short lA[128*LDW];
  __shared__ __align__(16) unsigned short lB[128*LDW];
  int b, t, brow, bcol;
  if(MODE == 0){
    int lin = blockIdx.x, x8 = lin & 7, q = lin >> 3;
    int blk = q & 63, g = (q >> 6) * 8 + x8;       // g in 0..111
    b = g / 7; t = g % 7;
    brow = (blk >> 3) << 7; bcol = (blk & 7) << 7;
  } else if(MODE == 2){
    int lin = blockIdx.x, x8 = lin & 7, q = lin >> 3;
    int blk = q & 63;
    b = (q >> 6) * 8 + x8; t = 0;                  // b in 0..15
    brow = (blk >> 3) << 7; bcol = (blk & 7) << 7;
  } else {
    b = blockIdx.z; t = tsel;
    brow = blockIdx.x * 128; bcol = blockIdx.y * 128;
  }
  int tA = (MODE==2) ? 0 : t+1;
  int tB = (MODE==2) ? 1 : t;
  const unsigned short* Ab = fbuf + ((size_t)(b*NT+tA)*NN + brow) * NC;
  const unsigned short* Bb = fbuf + ((size_t)(b*NT+tB)*NN + bcol) * NC;
  int tid = threadIdx.x, lane = tid & 63, w = tid >> 6, wr = w >> 1, wc = w & 1;
  f32x4 acc[4][4];
  #pragma unroll
  for(int m=0;m<4;m++)
    #pragma unroll
    for(int n=0;n<4;n++) acc[m][n] = (f32x4){0.f,0.f,0.f,0.f};

  for(int kk=0; kk<4; kk++){
    __syncthreads();
    stage_s(Ab + kk*32, NC, lA);
    stage_s(Bb + kk*32, NC, lB);
    __syncthreads();
    bf16x8 fa[4], fg[4];
    #pragma unroll
    for(int x=0;x<4;x++){ fa[x] = frag_s(lA, wr*64+x*16, lane); fg[x] = frag_s(lB, wc*64+x*16, lane); }
    #pragma unroll
    for(int m=0;m<4;m++)
      #pragma unroll
      for(int n=0;n<4;n++)
        acc[m][n] = __builtin_amdgcn_mfma_f32_16x16x32_bf16(fa[m], fg[n], acc[m][n], 0, 0, 0);
  }

  float e[4][4][4];
  #pragma unroll
  for(int m=0;m<4;m++)
    #pragma unroll
    for(int n=0;n<4;n++)
      #pragma unroll
      for(int j=0;j<4;j++) e[m][n][j] = __expf(acc[m][n][j] * INV_T);

  if(MODE == 0){
    float* cbt = cb + ((size_t)b*7 + t) * NN;
    float* rbt = rb + ((size_t)b*7 + t) * NN;
    #pragma unroll
    for(int m=0;m<4;m++)
      #pragma unroll
      for(int j=0;j<4;j++){
        float s = e[m][0][j]+e[m][1][j]+e[m][2][j]+e[m][3][j];
        s += __shfl_xor(s,1); s += __shfl_xor(s,2); s += __shfl_xor(s,4); s += __shfl_xor(s,8);
        if((lane & 15) == 0){
          int row = brow + wr*64 + m*16 + (lane>>4)*4 + j;
          atomicAdd(&cbt[row], s);
        }
      }
    #pragma unroll
    for(int n=0;n<4;n++){
      float s = 0.f;
      #pragma unroll
      for(int m=0;m<4;m++)
        #pragma unroll
        for(int j=0;j<4;j++) s += e[m][n][j];
      s += __shfl_xor(s,16); s += __shfl_xor(s,32);
      if((lane >> 4) == 0){
        int col = bcol + wc*64 + n*16 + lane;
        atomicAdd(&rbt[col], s);
      }
    }
    if(G && t >= 1){   // fused G_t store (big-ws path)
      unsigned short* Gt = G + ((size_t)(t-1)*NB + b) * ((size_t)NN*NN);
      #pragma unroll
      for(int m=0;m<4;m++)
        #pragma unroll
        for(int n=0;n<4;n++)
          #pragma unroll
          for(int j=0;j<4;j++){
            int row = brow + wr*64 + m*16 + (lane>>4)*4 + j;
            int col = bcol + wc*64 + n*16 + (lane&15);
            Gt[(size_t)row * NN + col] = f2bf(e[m][n][j]);
          }
    }
  } else if(MODE == 1){
    unsigned short* Gt = G + ((size_t)b << 20);
    #pragma unroll
    for(int m=0;m<4;m++)
      #pragma unroll
      for(int n=0;n<4;n++)
        #pragma unroll
        for(int j=0;j<4;j++){
          int row = brow + wr*64 + m*16 + (lane>>4)*4 + j;
          int col = bcol + wc*64 + n*16 + (lane&15);
          Gt[(size_t)row * NN + col] = f2bf(e[m][n][j]);
        }
  } else {
    const float* r0 = rb + (size_t)b*7*NN;
    const float* r1 = r0 + NN;
    const float* c0 = cb + (size_t)b*7*NN;
    unsigned short* Pt = P0 + ((size_t)b << 20);
    unsigned short* Mt = M0 + ((size_t)b << 20);
    float r1i[4], c0i[4];
    #pragma unroll
    for(int n=0;n<4;n++){
      int col = bcol + wc*64 + n*16 + (lane&15);
      r1i[n] = 1.f / r1[col];
      c0i[n] = 1.f / c0[col];
    }
    #pragma unroll
    for(int m=0;m<4;m++)
      #pragma unroll
      for(int j=0;j<4;j++){
        int row = brow + wr*64 + m*16 + (lane>>4)*4 + j;
        float r0i = 1.f / r0[row];
        #pragma unroll
        for(int n=0;n<4;n++){
          int col = bcol + wc*64 + n*16 + (lane&15);
          size_t idx = (size_t)row * NN + col;
          Pt[idx] = f2bf(e[m][n][j] * r0i * r1i[n]);
          Mt[idx] = f2bf(e[m][n][j] * c0i[n]);
        }
      }
  }
}

// ---------------- K4: fused dual chain GEMM, tile 128x256, BK=64, 512 thr ----------------
// Double-buffered LDS (128KB), T2 both-sides swizzle.
// 1D grid 512, 2-level XCD grouping: each XCD owns (b, cb-pair) groups of 16 blocks
//   -> G panels read 1x per XCD, P/M row-panels read by only 2 XCDs.
template<int LAST>
__global__ void __launch_bounds__(512, 2)
k_chain(const unsigned short* __restrict__ P, const unsigned short* __restrict__ M,
        const unsigned short* __restrict__ G,
        unsigned short* __restrict__ Pn, unsigned short* __restrict__ Mn,
        const float* __restrict__ rb, const float* __restrict__ cb,
        float* __restrict__ diag, int i)
{
  __shared__ __align__(16) unsigned short lP0[128*64], lM0[128*64], lG0[256*64];
  __shared__ __align__(16) unsigned short lP1[128*64], lM1[128*64], lG1[256*64];
  int lin = blockIdx.x, x8 = lin & 7, q = lin >> 3;
  int j = q & 15, g = (q >> 4) * 8 + x8;          // g in 0..31
  int b = g >> 1, cbp = g & 1;
  int row = j >> 1, cbk = cbp * 2 + (j & 1);
  size_t mb = (size_t)b << 20;
  int brow = row * 128, bcol = cbk * 256;
  const unsigned short* Pb = P + mb + (size_t)brow * NN;
  const unsigned short* Mb = M + mb + (size_t)brow * NN;
  const unsigned short* Gb = G + mb + (size_t)bcol * NN;
  int tid = threadIdx.x, lane = tid & 63, w = tid >> 6, wr = w >> 2, wc = w & 3;
  int l15 = lane & 15;

  // staging geometry: chunk = 16B; srow = tid>>3 (0..63); swizzled source chunk g8
  int srow = tid >> 3;
  int g8 = (((tid & 7) ^ (srow & 7)) << 3);   // ushort offset of swizzled 16B chunk
  int co0 = ((lane >> 4) ^ (lane & 7)) << 3;  // read-side swizzle base

  f32x4 aP[4][4], aM[4][4];
  #pragma unroll
  for(int m=0;m<4;m++)
    #pragma unroll
    for(int n=0;n<4;n++){ aP[m][n] = (f32x4){0.f,0.f,0.f,0.f}; aM[m][n] = (f32x4){0.f,0.f,0.f,0.f}; }

  auto stage = [&](int kk, unsigned short* lp, unsigned short* lm, unsigned short* lg){
    const unsigned short* ps = Pb + kk*64 + g8;
    const unsigned short* ms = Mb + kk*64 + g8;
    const unsigned short* gs = Gb + kk*64 + g8;
    gload16(ps + (size_t)srow*NN,      lp + tid*8);
    gload16(ps + (size_t)(srow+64)*NN, lp + (tid+512)*8);
    gload16(ms + (size_t)srow*NN,      lm + tid*8);
    gload16(ms + (size_t)(srow+64)*NN, lm + (tid+512)*8);
    #pragma unroll
    for(int c = 0; c < 4; c++)
      gload16(gs + (size_t)(srow+c*64)*NN, lg + (tid+c*512)*8);
  };

  auto compute = [&](const unsigned short* lp, const unsigned short* lm, const unsigned short* lg){
    #pragma unroll
    for(int kh = 0; kh < 2; kh++){
      int cOff = co0 ^ (kh << 5);
      bf16x8 fP[4], fM[4], fG[4];
      #pragma unroll
      for(int x=0;x<4;x++){
        fP[x] = *(const bf16x8*)(lp + (wr*64 + x*16 + l15)*64 + cOff);
        fM[x] = *(const bf16x8*)(lm + (wr*64 + x*16 + l15)*64 + cOff);
        fG[x] = *(const bf16x8*)(lg + (wc*64 + x*16 + l15)*64 + cOff);
      }
      #pragma unroll
      for(int m=0;m<4;m++)
        #pragma unroll
        for(int n=0;n<4;n++){
          aP[m][n] = __builtin_amdgcn_mfma_f32_16x16x32_bf16(fP[m], fG[n], aP[m][n], 0, 0, 0);
          aM[m][n] = __builtin_amdgcn_mfma_f32_16x16x32_bf16(fM[m], fG[n], aM[m][n], 0, 0, 0);
        }
    }
  };

  stage(0, lP0, lM0, lG0);
  __syncthreads();
  #pragma unroll 1
  for(int kk = 0; kk < 16; kk += 2){
    if(kk + 1 < 16) stage(kk+1, lP1, lM1, lG1);
    compute(lP0, lM0, lG0);
    __syncthreads();
    if(kk + 2 < 16) stage(kk+2, lP0, lM0, lG0);
    compute(lP1, lM1, lG1);
    __syncthreads();
  }

  const float* ccur = cb + ((size_t)b*7 + i) * NN;
  const float* rnxt = rb + ((size_t)b*7 + i + 1) * NN;  // not dereferenced when LAST
  float ci[4], ri[4];
  #pragma unroll
  for(int n=0;n<4;n++){
    int col = bcol + wc*64 + n*16 + l15;
    ci[n] = 1.f / ccur[col];
    ri[n] = LAST ? 0.f : 1.f / rnxt[col];
  }
  float* dg = diag + ((size_t)b*6 + (i-1)) * NN;
  #pragma unroll
  for(int m=0;m<4;m++)
    #pragma unroll
    for(int j4=0;j4<4;j4++){
      int rowi = brow + wr*64 + m*16 + (lane>>4)*4 + j4;
      float s = 0.f;
      #pragma unroll
      for(int n=0;n<4;n++){
        int col = bcol + wc*64 + n*16 + l15;
        float vP = aP[m][n][j4];
        float vM = aM[m][n][j4] * ci[n];
        s += vP * vM;
        if(!LAST){
          size_t idx = mb + (size_t)rowi * NN + col;
          Pn[idx] = f2bf(vP * ri[n]);
          Mn[idx] = f2bf(vM);
        }
      }
      s += __shfl_xor(s,1); s += __shfl_xor(s,2); s += __shfl_xor(s,4); s += __shfl_xor(s,8);
      if((lane&15)==0) atomicAdd(&dg[rowi], s);
    }
}

// ---------------- K5: loss = -mean log(diag + eps) ----------------
__global__ void k_loss(const float* __restrict__ diag, float* __restrict__ out){
  __shared__ float red[16];
  float s = 0.f;
  for(int idx = threadIdx.x; idx < NB*6*NN; idx += 1024) s += __logf(diag[idx] + 1e-20f);
  s += __shfl_xor(s,1); s += __shfl_xor(s,2); s += __shfl_xor(s,4);
  s += __shfl_xor(s,8); s += __shfl_xor(s,16); s += __shfl_xor(s,32);
  if((threadIdx.x & 63) == 0) red[threadIdx.x >> 6] = s;
  __syncthreads();
  if(threadIdx.x == 0){
    float t = 0.f;
    for(int k = 0; k < 16; k++) t += red[k];
    out[0] = -t / (6.0f * NB * NN);
  }
}

__global__ void k_fail(float* out){ out[0] = 1.0e9f; }

extern "C" void kernel_launch(void* const* d_in, const int* in_sizes, int n_in,
                              void* d_out, int out_size, void* d_ws, size_t ws_size,
                              hipStream_t stream) {
  const float* feats = (const float*)d_in[0];
  float* out = (float*)d_out;
  char* ws = (char*)d_ws;
  size_t off = 0;
  auto alloc = [&](size_t bytes) -> char* {
    char* p = ws + off; off += (bytes + 255) & ~(size_t)255; return p;
  };
  const size_t plane = (size_t)NB * NN * NN * 2;                        // 33.5 MB
  unsigned short* fb = (unsigned short*)alloc((size_t)NB*NT*NN*NC*2);   // 33.5 MB
  unsigned short* Pa   = (unsigned short*)alloc(plane);
  unsigned short* Pbuf = (unsigned short*)alloc(plane);
  unsigned short* Ma   = (unsigned short*)alloc(plane);
  unsigned short* Mbuf = (unsigned short*)alloc(plane);
  float* rb = (float*)alloc((size_t)NB*7*NN*4);
  float* cb = (float*)alloc((size_t)NB*7*NN*4);
  float* dg = (float*)alloc((size_t)NB*6*NN*4);
  if(off + plane > ws_size){ k_fail<<<1,1,0,stream>>>(out); return; }
  bool big = (off + 6*plane) <= ws_size;
  unsigned short* G = (unsigned short*)alloc(big ? 6*plane : plane);

  // zero the accumulated buffers (r, c, diag are contiguous, 256B-aligned sizes)
  hipMemsetAsync(rb, 0, (size_t)NB*7*NN*4 + (size_t)NB*7*NN*4 + (size_t)NB*6*NN*4, stream);

  k_norm<<<dim3(4, NB*NT), 256, 0, stream>>>(feats, fb);
  gemm_small<0><<<dim3(7168), 256, 0, stream>>>(fb, big ? G : nullptr, rb, cb, nullptr, nullptr, 0);
  gemm_small<2><<<dim3(1024), 256, 0, stream>>>(fb, nullptr, rb, cb, Pa, Ma, 0);

  unsigned short *Pold = Pa, *Mold = Ma, *Pnew = Pbuf, *Mnew = Mbuf;
  for(int i = 1; i <= 6; i++){
    unsigned short* Gi;
    if(big){
      Gi = G + (size_t)(i-1) * NB * NN * NN;
    } else {
      gemm_small<1><<<dim3(8,8,NB), 256, 0, stream>>>(fb, G, rb, cb, nullptr, nullptr, i);
      Gi = G;
    }
    if(i < 6)
      k_chain<0><<<dim3(512), 512, 0, stream>>>(Pold, Mold, Gi, Pnew, Mnew, rb, cb, dg, i);
    else
      k_chain<1><<<dim3(512), 512, 0, stream>>>(Pold, Mold, Gi, Pnew, Mnew, rb, cb, dg, i);
    unsigned short* tp = Pold; Pold = Pnew; Pnew = tp;
    unsigned short* tm = Mold; Mold = Mnew; Mnew = tm;
  }
  k_loss<<<1, 1024, 0, stream>>>(dg, out);
}